// Round 7
// baseline (453.207 us; speedup 1.0000x reference)
//
#include <hip/hip_runtime.h>
#include <hip/hip_bf16.h>
#include <stdint.h>

namespace {

constexpr int D    = 512;
constexpr int S    = 1536;
constexpr int N    = S + 1;      // 1537
constexpr int L    = 4;
constexpr int H    = 4;
constexpr int R    = 32;
constexpr int W    = 128;
constexpr int HFF  = 1024;
constexpr float EPS = 1e-5f;

// attention: 4 tokens/block, shared neighbor span
constexpr int TB   = 4;
constexpr int NB4  = (N + TB - 1) / TB;   // 385 blocks
constexpr int SP   = 133;    // c=0..131 window span (g = n0-W+c), c=132 anchor
constexpr int SPAD = 137;    // padded row stride (2-way bank alias)

constexpr int GS2  = 1024;   // setup kernel grid
constexpr int SLABR = 528;   // gemm64 slab stride: 64 rows * 8 ushorts + 16 pad
constexpr int BK   = 128;    // gemm64 K-step

// in-attn QK gemm tiles
constexpr int KROWS = 144;               // 9 row-tiles of 16 (window 0..132 used)
constexpr int SLABK = KROWS * 8 + 8;     // 1160 ushorts per kb-chunk
constexpr int BSLAB = 64 * 8 + 8;        // 520

typedef __attribute__((ext_vector_type(8))) short short8;
typedef __attribute__((ext_vector_type(4))) float floatx4;

__device__ inline ushort f2bf(float x){
  __hip_bfloat16 h = __float2bfloat16(x);
  return *reinterpret_cast<ushort*>(&h);
}
__device__ inline float bf2f(uint u){
  union { uint u; float f; } c; c.u = u << 16; return c.f;
}

// ---------------- reductions ------------------------------------------------
__device__ inline float wave_sum(float v){
#pragma unroll
  for (int o = 32; o; o >>= 1) v += __shfl_xor(v, o, 64);
  return v;
}
__device__ inline float wave_max(float v){
#pragma unroll
  for (int o = 32; o; o >>= 1) v = fmaxf(v, __shfl_xor(v, o, 64));
  return v;
}
__device__ inline float block_sum(float v, float* scr){
  v = wave_sum(v);
  __syncthreads();
  if ((threadIdx.x & 63) == 0) scr[threadIdx.x >> 6] = v;
  __syncthreads();
  return scr[0] + scr[1] + scr[2] + scr[3];
}

// ---------------- fused setup: embed+LN+state | pack wqk | transpose ffn ----
__global__ __launch_bounds__(256) void setup_kernel(
    const int* __restrict__ ids, const float* __restrict__ embed,
    const float* __restrict__ pos, const float* __restrict__ g,
    const float* __restrict__ b, const float* __restrict__ anchor_val,
    const float* __restrict__ anchor_state, const float* __restrict__ state_w,
    const float* __restrict__ state_b, float* __restrict__ val,
    ushort* __restrict__ valbf, float* __restrict__ state,
    const float* __restrict__ wq, const float* __restrict__ wk,
    ushort* __restrict__ wqkbf,
    const float* __restrict__ ffn_w1, const float* __restrict__ ffn_w2,
    ushort* __restrict__ w1t, ushort* __restrict__ w2t)
{
  __shared__ float scr[4];
  __shared__ float tile[32 * 33];
  const int t = threadIdx.x;

  // --- embed + input LN + tok_state (one row per block-iteration)
  for (int n = blockIdx.x; n < N; n += GS2){
    if (n == 0){
      float a0 = anchor_val[t], a1 = anchor_val[t + 256];
      val[t] = a0; val[t + 256] = a1;
      valbf[t] = f2bf(a0); valbf[t + 256] = f2bf(a1);
      if (t == 0) state[0] = anchor_state[0];
      continue;
    }
    int tp = n - 1;
    int id = ids[tp];
    float x0 = embed[(size_t)id * D + t]       + pos[tp * D + t];
    float x1 = embed[(size_t)id * D + t + 256] + pos[tp * D + t + 256];
    float mean = block_sum(x0 + x1, scr) * (1.f / D);
    float var  = block_sum(x0 * x0 + x1 * x1, scr) * (1.f / D) - mean * mean;
    float rs   = rsqrtf(var + EPS);
    float y0 = (x0 - mean) * rs * g[t]       + b[t];
    float y1 = (x1 - mean) * rs * g[t + 256] + b[t + 256];
    val[n * D + t]       = y0;
    val[n * D + t + 256] = y1;
    valbf[n * D + t]       = f2bf(y0);
    valbf[n * D + t + 256] = f2bf(y1);
    float ts = block_sum(y0 * state_w[t] + y1 * state_w[t + 256], scr);
    if (t == 0) state[n] = ts + state_b[0];
  }

  // --- pack wq/wk -> bf16 [l][c][d], c = q(0..127)|k(128..255)
  for (int i = blockIdx.x * 256 + t; i < L * 256 * D; i += GS2 * 256){
    int d = i & 511;
    int c = (i >> 9) & 255;
    int l = i >> 17;
    int cc = c & 127;
    int h = cc >> 5, r = cc & 31;
    const float* src = (c < 128) ? wq : wk;
    wqkbf[i] = f2bf(src[((l * H + h) * D + d) * R + r]);
  }
  __syncthreads();

  // --- transpose ffn weights to bf16 [cols][rows]
  const int tx = t & 31, ty = t >> 5;
  for (int tl = blockIdx.x; tl < 2 * L * 512; tl += GS2){
    const float* s; ushort* dd; int rows, cols, c0, r0;
    if (tl < 2048){
      int ll = tl >> 9, i = tl & 511;
      rows = D; cols = HFF;
      s  = ffn_w1 + (size_t)ll * D * HFF;
      dd = w1t   + (size_t)ll * D * HFF;
      c0 = (i & 31) << 5; r0 = (i >> 5) << 5;
    } else {
      int tl2 = tl - 2048;
      int ll = tl2 >> 9, i = tl2 & 511;
      rows = HFF; cols = D;
      s  = ffn_w2 + (size_t)ll * D * HFF;
      dd = w2t   + (size_t)ll * D * HFF;
      c0 = (i & 15) << 5; r0 = (i >> 4) << 5;
    }
    __syncthreads();
    for (int rr = ty; rr < 32; rr += 8)
      tile[rr * 33 + tx] = s[(size_t)(r0 + rr) * cols + c0 + tx];
    __syncthreads();
    for (int rr = ty; rr < 32; rr += 8)
      dd[(size_t)(c0 + rr) * rows + r0 + tx] = f2bf(tile[tx * 33 + rr]);
  }
}

// ---------------- bf16 MFMA GEMM, 64x64 tile, BK=128, 2-phase pipelined -----
// (R6-verified) C = act(A*Bt^T + bias)(+resid).
template<int ACT>
__global__ __launch_bounds__(256) void gemm64(
    const ushort* __restrict__ A, const ushort* __restrict__ Bt,
    const float* __restrict__ bias, const float* __restrict__ resid,
    float* __restrict__ C, ushort* __restrict__ Cbf,
    int M, int Kd, int Nc)
{
  __shared__ ushort As[16 * SLABR];
  __shared__ ushort Bs[16 * SLABR];
  const int row0 = blockIdx.y * 64;
  const int col0 = blockIdx.x * 64;
  const int t = threadIdx.x;
  const int lane = t & 63, w = t >> 6;
  const int wr = w & 1, wc = w >> 1;
  const int q = lane >> 4, lm = lane & 15;

  const int srow = t >> 3, skb = t & 7;
  int ar0 = min(row0 + srow,      M - 1);
  int ar1 = min(row0 + srow + 32, M - 1);
  const ushort* agA0 = A  + (size_t)ar0 * Kd + skb * 8;
  const ushort* agA1 = A  + (size_t)ar1 * Kd + skb * 8;
  const ushort* agB0 = Bt + (size_t)(col0 + srow) * Kd + skb * 8;
  const ushort* agB1 = Bt + (size_t)(col0 + srow + 32) * Kd + skb * 8;
  ushort* asw00 = &As[ skb      * SLABR +  srow       * 8];
  ushort* asw01 = &As[(skb + 8) * SLABR +  srow       * 8];
  ushort* asw10 = &As[ skb      * SLABR + (srow + 32) * 8];
  ushort* asw11 = &As[(skb + 8) * SLABR + (srow + 32) * 8];
  ushort* bsw00 = &Bs[ skb      * SLABR +  srow       * 8];
  ushort* bsw01 = &Bs[(skb + 8) * SLABR +  srow       * 8];
  ushort* bsw10 = &Bs[ skb      * SLABR + (srow + 32) * 8];
  ushort* bsw11 = &Bs[(skb + 8) * SLABR + (srow + 32) * 8];

  const ushort* arp = &As[(wr * 32 + lm) * 8];
  const ushort* brp = &Bs[(wc * 32 + lm) * 8];

  floatx4 acc[2][2];
#pragma unroll
  for (int m = 0; m < 2; ++m)
#pragma unroll
    for (int n = 0; n < 2; ++n) acc[m][n] = {0.f, 0.f, 0.f, 0.f};

  const int nk0 = Kd / BK;
  uint4 pa0, pa1, pa2, pa3, pb0, pb1, pb2, pb3;
  pa0 = *(const uint4*)(agA0);      pa1 = *(const uint4*)(agA0 + 64);
  pa2 = *(const uint4*)(agA1);      pa3 = *(const uint4*)(agA1 + 64);
  pb0 = *(const uint4*)(agB0);      pb1 = *(const uint4*)(agB0 + 64);
  pb2 = *(const uint4*)(agB1);      pb3 = *(const uint4*)(agB1 + 64);

  for (int i = 0; i < nk0; ++i){
    *(uint4*)asw00 = pa0; *(uint4*)asw01 = pa1;
    *(uint4*)asw10 = pa2; *(uint4*)asw11 = pa3;
    *(uint4*)bsw00 = pb0; *(uint4*)bsw01 = pb1;
    *(uint4*)bsw10 = pb2; *(uint4*)bsw11 = pb3;
    __syncthreads();
    if (i + 1 < nk0){
      const int ko = (i + 1) * BK;
      pa0 = *(const uint4*)(agA0 + ko);      pa1 = *(const uint4*)(agA0 + ko + 64);
      pa2 = *(const uint4*)(agA1 + ko);      pa3 = *(const uint4*)(agA1 + ko + 64);
      pb0 = *(const uint4*)(agB0 + ko);      pb1 = *(const uint4*)(agB0 + ko + 64);
      pb2 = *(const uint4*)(agB1 + ko);      pb3 = *(const uint4*)(agB1 + ko + 64);
    }
#pragma unroll
    for (int kk = 0; kk < 4; ++kk){
      const int kb = (kk * 4 + q) * SLABR;
      short8 am0 = *(const short8*)(arp + kb);
      short8 am1 = *(const short8*)(arp + kb + 16 * 8);
      short8 bn0 = *(const short8*)(brp + kb);
      short8 bn1 = *(const short8*)(brp + kb + 16 * 8);
      acc[0][0] = __builtin_amdgcn_mfma_f32_16x16x32_bf16(am0, bn0, acc[0][0], 0, 0, 0);
      acc[0][1] = __builtin_amdgcn_mfma_f32_16x16x32_bf16(am0, bn1, acc[0][1], 0, 0, 0);
      acc[1][0] = __builtin_amdgcn_mfma_f32_16x16x32_bf16(am1, bn0, acc[1][0], 0, 0, 0);
      acc[1][1] = __builtin_amdgcn_mfma_f32_16x16x32_bf16(am1, bn1, acc[1][1], 0, 0, 0);
    }
    __syncthreads();
  }

#pragma unroll
  for (int m = 0; m < 2; ++m){
#pragma unroll
    for (int n = 0; n < 2; ++n){
      int col = col0 + wc * 32 + n * 16 + lm;
#pragma unroll
      for (int r = 0; r < 4; ++r){
        int row = row0 + wr * 32 + m * 16 + q * 4 + r;
        if (row >= M) continue;
        float v = acc[m][n][r] + (bias ? bias[col] : 0.f);
        if (ACT == 1) v = 0.5f * v * (1.f + erff(v * 0.70710678118654752f));
        if (resid) v += resid[(size_t)row * Nc + col];
        size_t o = (size_t)row * Nc + col;
        if (C)   C[o] = v;
        if (Cbf) Cbf[o] = f2bf(v);
      }
    }
  }
}

// ---------------- fused QK projection + attention, 4 tokens per block -------
// Computes q (own 4 rows x 128 ch) and k (window rows x 128 ch, two halves)
// in-block via MFMA from val0bf x wqk — replaces the separate QK GEMM
// dispatch. ~34x k-halo redundancy costs ~6.7us device MFMA per layer but
// removes a ~10us dispatch boundary. Fragment geometry identical to gemm64
// (verified): A-frag row=lm, chunk=(kk*4+q); C col=lm, row=q*4+r.
__global__ __launch_bounds__(256) void qkattn_kernel(
    const ushort* __restrict__ wqk,   // layer base [256][512] bf16: q rows 0..127, k 128..255
    const float* __restrict__ val0,
    const ushort* __restrict__ val0bf, const float* __restrict__ state_in,
    float* __restrict__ val1, ushort* __restrict__ x2bf,
    float* __restrict__ state_out,
    const float* __restrict__ gate_p, const float* __restrict__ lng,
    const float* __restrict__ lnb, const float* __restrict__ ln2g,
    const float* __restrict__ ln2b)
{
  __shared__ float kg[64 * SPAD];   // [ch][c] f32; reused as xbuf[4][520] later
  __shared__ float qsh[TB * 128];
  __shared__ float ssh[16 * SPAD];  // [tok*4+h][c]
  __shared__ float ash[TB * SPAD];  // a then e, row per token
  __shared__ ushort As2[8 * SLABK]; // [kb][row*8]: k-gemm A rows 0..143 / q-gemm B ch 0..127
  __shared__ ushort Bs2[8 * BSLAB]; // [kb][ch*8]:  k-gemm B ch 0..63  / q-gemm A rows 0..15
  const int n0 = blockIdx.x * TB;
  const int t = threadIdx.x;
  const int w = t >> 6, l = t & 63;   // wave = token index (softmax phase)
  const int q = l >> 4, lm = l & 15;  // mfma lane decomposition
  const float gate = gate_p[0];
  const float scale = 0.17677669529663687f;  // 1/sqrt(32)

  // ---- q-GEMM: own 4 tokens (row-tile 0 of 16) x 128 q-channels, K=512
  {
    floatx4 accq0 = {0.f,0.f,0.f,0.f}, accq1 = {0.f,0.f,0.f,0.f};
    for (int ks = 0; ks < 8; ++ks){
      if (t < 128){
        int row = t >> 3, kb = t & 7;
        int g = min(n0 + row, N - 1);
        *(uint4*)&Bs2[kb * BSLAB + row * 8] =
            *(const uint4*)&val0bf[(size_t)g * D + ks * 64 + kb * 8];
      }
#pragma unroll
      for (int s = 0; s < 4; ++s){
        int slot = t + s * 256;
        int ch = slot >> 3, kb = slot & 7;
        *(uint4*)&As2[kb * SLABK + ch * 8] =
            *(const uint4*)&wqk[(size_t)ch * D + ks * 64 + kb * 8];
      }
      __syncthreads();
#pragma unroll
      for (int kk = 0; kk < 2; ++kk){
        int kc = kk * 4 + q;
        short8 a  = *(const short8*)&Bs2[kc * BSLAB + lm * 8];
        short8 b0 = *(const short8*)&As2[kc * SLABK + ((2 * w)     * 16 + lm) * 8];
        short8 b1 = *(const short8*)&As2[kc * SLABK + ((2 * w + 1) * 16 + lm) * 8];
        accq0 = __builtin_amdgcn_mfma_f32_16x16x32_bf16(a, b0, accq0, 0, 0, 0);
        accq1 = __builtin_amdgcn_mfma_f32_16x16x32_bf16(a, b1, accq1, 0, 0, 0);
      }
      __syncthreads();
    }
    if (q == 0){   // rows 0..3 = our 4 tokens
#pragma unroll
      for (int r = 0; r < 4; ++r){
        qsh[r * 128 + (2 * w)     * 16 + lm] = accq0[r];
        qsh[r * 128 + (2 * w + 1) * 16 + lm] = accq1[r];
      }
    }
  }
  __syncthreads();

  // ---- per half: k-GEMM (window rows x 64 k-channels) then scores
  for (int half = 0; half < 2; ++half){
    floatx4 acck[9];
#pragma unroll
    for (int tr = 0; tr < 9; ++tr) acck[tr] = {0.f, 0.f, 0.f, 0.f};
    for (int ks = 0; ks < 8; ++ks){
#pragma unroll
      for (int s = 0; s < 5; ++s){
        int slot = t + s * 256;
        if (slot < KROWS * 8){
          int row = slot >> 3, kb = slot & 7;
          int g = (row == 132) ? 0 : min(max(n0 - W + row, 0), N - 1);
          *(uint4*)&As2[kb * SLABK + row * 8] =
              *(const uint4*)&val0bf[(size_t)g * D + ks * 64 + kb * 8];
        }
      }
#pragma unroll
      for (int s = 0; s < 2; ++s){
        int slot = t + s * 256;
        int ch = slot >> 3, kb = slot & 7;
        *(uint4*)&Bs2[kb * BSLAB + ch * 8] =
            *(const uint4*)&wqk[(size_t)(128 + half * 64 + ch) * D + ks * 64 + kb * 8];
      }
      __syncthreads();
#pragma unroll
      for (int kk = 0; kk < 2; ++kk){
        int kc = kk * 4 + q;
        short8 b = *(const short8*)&Bs2[kc * BSLAB + (w * 16 + lm) * 8];
#pragma unroll
        for (int tr = 0; tr < 9; ++tr){
          short8 a = *(const short8*)&As2[kc * SLABK + (tr * 16 + lm) * 8];
          acck[tr] = __builtin_amdgcn_mfma_f32_16x16x32_bf16(a, b, acck[tr], 0, 0, 0);
        }
      }
      __syncthreads();
    }
    // commit k to kg[ch][c]; C layout: col(=ch within wave's 16)=lm, row(=c)=q*4+r
    {
      int ch = w * 16 + lm;
#pragma unroll
      for (int tr = 0; tr < 9; ++tr){
        int cbase = tr * 16 + q * 4;
#pragma unroll
        for (int r = 0; r < 4; ++r){
          int c = cbase + r;
          if (c <= 132) kg[ch * SPAD + c] = acck[tr][r];
        }
      }
    }
    __syncthreads();
    // scores (unchanged)
    for (int tk = t; tk < TB * 2 * SP; tk += 256){
      int c = tk % SP;
      int th = tk / SP;            // 0..7
      int tok = th & 3, hh = th >> 2;
      int h = half * 2 + hh;
      const float* qs = &qsh[tok * 128 + h * 32];
      const float* ks2 = &kg[hh * 32 * SPAD + c];
      float acc = 0.f;
#pragma unroll
      for (int r = 0; r < 32; ++r) acc += qs[r] * ks2[r * SPAD];
      ssh[(tok * 4 + h) * SPAD + c] = acc * scale;
    }
    __syncthreads();
  }

  // ---- per-(tok,c) head softmax -> a
  for (int i = t; i < TB * SP; i += 256){
    int tok = i / SP, c = i - tok * SP;
    const float* sr = &ssh[tok * 4 * SPAD + c];
    float s0 = sr[0], s1 = sr[SPAD], s2 = sr[2 * SPAD], s3 = sr[3 * SPAD];
    float a0 = fabsf(s0), a1 = fabsf(s1), a2 = fabsf(s2), a3 = fabsf(s3);
    float m = fmaxf(fmaxf(a0, a1), fmaxf(a2, a3));
    float w0 = expf(a0 - m), w1 = expf(a1 - m), w2 = expf(a2 - m), w3 = expf(a3 - m);
    ash[tok * SPAD + c] = (s0 * w0 + s1 * w1 + s2 * w2 + s3 * w3) / (w0 + w1 + w2 + w3);
  }
  __syncthreads();

  // ---- per-token signed softmax over span (wave w <-> token w), e in place
  {
    const int n = n0 + w;
    float* arow = &ash[w * SPAD];
    float a0 = arow[l];
    float a1 = arow[64 + l];
    float a2 = (l < 5) ? arow[128 + l] : 0.f;
    bool ok0 = (l >= w) && (n0 - W + l >= 0);
    bool ok1 = (n0 - W + 64 + l >= 0);
    bool ok2;
    if (l < 4)       ok2 = (l <= w);          // window col 128+l, g = n0+l >= 0
    else if (l == 4) ok2 = (n > W);           // anchor (c=132)
    else             ok2 = false;
    float cand = -3.4e38f;
    if (ok0) cand = fabsf(a0);
    if (ok1) cand = fmaxf(cand, fabsf(a1));
    if (ok2) cand = fmaxf(cand, fabsf(a2));
    float m = wave_max(cand);
    float e0 = ok0 ? expf(fabsf(a0) - m) : 0.f;
    float e1 = ok1 ? expf(fabsf(a1) - m) : 0.f;
    float e2 = ok2 ? expf(fabsf(a2) - m) : 0.f;
    float inv = 1.f / wave_sum(e0 + e1 + e2);
    int g0 = min(max(n0 - W + l, 0), N - 1);
    int g1 = min(max(n0 - W + 64 + l, 0), N - 1);
    int g2 = (l < 4) ? min(n0 + l, N - 1) : 0;
    float sg0 = (a0 > 0.f) ? 1.f : ((a0 < 0.f) ? -1.f : 0.f);
    float sg1 = (a1 > 0.f) ? 1.f : ((a1 < 0.f) ? -1.f : 0.f);
    float sg2 = (a2 > 0.f) ? 1.f : ((a2 < 0.f) ? -1.f : 0.f);
    float t0 = sg0 * e0 * inv * state_in[g0];
    float t1 = sg1 * e1 * inv * state_in[g1];
    float t2 = (l < 5) ? sg2 * e2 * inv * state_in[g2] : 0.f;
    arow[l] = t0;
    arow[64 + l] = t1;
    if (l < 5) arow[128 + l] = t2;
    float ds = wave_sum(t0 + t1 + t2);
    if (l == 0 && n < N) state_out[n] = state_in[n] + gate * ds;
  }
  __syncthreads();

  // ---- d_val: stream span rows once (bf16), 4 accumulators per thread
  float acc[TB][2];
#pragma unroll
  for (int k = 0; k < TB; ++k){ acc[k][0] = 0.f; acc[k][1] = 0.f; }
  {
    const int d0 = 2 * t;
    for (int c = 0; c < SP; ++c){
      int g = (c == 132) ? 0 : min(max(n0 - W + c, 0), N - 1);
      uint v = *(const uint*)&val0bf[(size_t)g * D + d0];
      float vx = bf2f(v & 0xffffu), vy = bf2f(v >> 16);
#pragma unroll
      for (int k = 0; k < TB; ++k){
        float e = ash[k * SPAD + c];
        acc[k][0] += e * vx;
        acc[k][1] += e * vy;
      }
    }
  }
  // residual into xbuf (reuse kg; kg dead after scores)
  float* xbuf = kg;    // [4][520]
  {
    const int d0 = 2 * t;
#pragma unroll
    for (int k = 0; k < TB; ++k){
      int nc = min(n0 + k, N - 1);
      float2 vv = *(const float2*)&val0[(size_t)nc * D + d0];
      xbuf[k * 520 + d0]     = vv.x + gate * acc[k][0];
      xbuf[k * 520 + d0 + 1] = vv.y + gate * acc[k][1];
    }
  }
  __syncthreads();

  // ---- LN1 -> val1, LN2 -> x2bf (wave per token, 8 dims per lane)
  {
    const int n = n0 + w;
    const int d = l * 8;
    const float* xr = &xbuf[w * 520 + d];
    float x[8];
#pragma unroll
    for (int j = 0; j < 8; ++j) x[j] = xr[j];
    float s1 = 0.f, s2 = 0.f;
#pragma unroll
    for (int j = 0; j < 8; ++j){ s1 += x[j]; s2 += x[j] * x[j]; }
    s1 = wave_sum(s1); s2 = wave_sum(s2);
    float mean = s1 * (1.f / D);
    float var  = s2 * (1.f / D) - mean * mean;
    float rs   = rsqrtf(var + EPS);
    float y[8];
    float u1 = 0.f, u2 = 0.f;
#pragma unroll
    for (int j = 0; j < 8; ++j){
      float yv = (x[j] - mean) * rs * lng[d + j] + lnb[d + j];
      y[j] = yv; u1 += yv; u2 += yv * yv;
    }
    u1 = wave_sum(u1); u2 = wave_sum(u2);
    float mean2 = u1 * (1.f / D);
    float var2  = u2 * (1.f / D) - mean2 * mean2;
    float rs2   = rsqrtf(var2 + EPS);
    if (n < N){
      *(float4*)&val1[(size_t)n * D + d]     = make_float4(y[0], y[1], y[2], y[3]);
      *(float4*)&val1[(size_t)n * D + d + 4] = make_float4(y[4], y[5], y[6], y[7]);
      uint4 pk;
      uint z0 = f2bf((y[0] - mean2) * rs2 * ln2g[d + 0] + ln2b[d + 0]);
      uint z1 = f2bf((y[1] - mean2) * rs2 * ln2g[d + 1] + ln2b[d + 1]);
      uint z2 = f2bf((y[2] - mean2) * rs2 * ln2g[d + 2] + ln2b[d + 2]);
      uint z3 = f2bf((y[3] - mean2) * rs2 * ln2g[d + 3] + ln2b[d + 3]);
      uint z4 = f2bf((y[4] - mean2) * rs2 * ln2g[d + 4] + ln2b[d + 4]);
      uint z5 = f2bf((y[5] - mean2) * rs2 * ln2g[d + 5] + ln2b[d + 5]);
      uint z6 = f2bf((y[6] - mean2) * rs2 * ln2g[d + 6] + ln2b[d + 6]);
      uint z7 = f2bf((y[7] - mean2) * rs2 * ln2g[d + 7] + ln2b[d + 7]);
      pk.x = z0 | (z1 << 16); pk.y = z2 | (z3 << 16);
      pk.z = z4 | (z5 << 16); pk.w = z6 | (z7 << 16);
      *(uint4*)&x2bf[(size_t)n * D + d] = pk;
    }
  }
}

} // anonymous namespace

extern "C" void kernel_launch(void* const* d_in, const int* in_sizes, int n_in,
                              void* d_out, int out_size, void* d_ws, size_t ws_size,
                              hipStream_t stream)
{
  (void)in_sizes; (void)n_in; (void)out_size; (void)ws_size;
  const int*   ids          = (const int*)d_in[0];
  const float* embed        = (const float*)d_in[1];
  const float* pos_emb      = (const float*)d_in[2];
  const float* ln_in_g      = (const float*)d_in[3];
  const float* ln_in_b      = (const float*)d_in[4];
  const float* anchor_state = (const float*)d_in[5];
  const float* anchor_val   = (const float*)d_in[6];
  const float* state_w      = (const float*)d_in[7];
  const float* state_b      = (const float*)d_in[8];
  const float* wq           = (const float*)d_in[9];
  const float* wk           = (const float*)d_in[10];
  const float* gate         = (const float*)d_in[11];
  const float* ln_g         = (const float*)d_in[12];
  const float* ln_b         = (const float*)d_in[13];
  const float* ffn_w1       = (const float*)d_in[14];
  const float* ffn_b1       = (const float*)d_in[15];
  const float* ffn_w2       = (const float*)d_in[16];
  const float* ffn_b2       = (const float*)d_in[17];
  const float* ln2_g        = (const float*)d_in[18];
  const float* ln2_b        = (const float*)d_in[19];
  float* out = (float*)d_out;

  float* wsf  = (float*)d_ws;
  float* val0 = wsf;  wsf += (size_t)N * D;      // layer input fp32 (residual)
  float* val1 = wsf;  wsf += (size_t)N * D;      // post-attn+LN1 (FFN2 residual)
  ushort* wsu   = (ushort*)wsf;
  ushort* val0bf = wsu;  wsu += (size_t)N * D;   // bf16 layer input
  ushort* x2bf   = wsu;  wsu += (size_t)N * D;   // bf16 LN2 out (FFN1 A)
  ushort* hbf    = wsu;  wsu += (size_t)N * HFF; // bf16 gelu out (FFN2 A)
  ushort* wqkbf  = wsu;  wsu += (size_t)L * 256 * D;
  ushort* w1t    = wsu;  wsu += (size_t)L * HFF * D;
  ushort* w2t    = wsu;  wsu += (size_t)L * HFF * D;
  float* st0 = (float*)wsu;
  float* st1 = st0 + N;

  setup_kernel<<<GS2, 256, 0, stream>>>(
      ids, embed, pos_emb, ln_in_g, ln_in_b, anchor_val, anchor_state,
      state_w, state_b, val0, val0bf, st0,
      wq, wk, wqkbf, ffn_w1, ffn_w2, w1t, w2t);

  float* sin_  = st0;
  float* sout_ = st1;
  const int MT64 = (N + 63) / 64;   // 25 row tiles
  for (int l = 0; l < L; ++l){
    qkattn_kernel<<<NB4, 256, 0, stream>>>(
        wqkbf + (size_t)l * 256 * D, val0, val0bf, sin_, val1, x2bf,
        sout_, gate + l, ln_g + l * D, ln_b + l * D, ln2_g + l * D,
        ln2_b + l * D);
    gemm64<1><<<dim3(HFF / 64, MT64), 256, 0, stream>>>(
        x2bf, w1t + (size_t)l * HFF * D, ffn_b1 + l * HFF, nullptr,
        nullptr, hbf, N, D, HFF);
    float* dst = (l == L - 1) ? out : val0;
    gemm64<0><<<dim3(D / 64, MT64), 256, 0, stream>>>(
        hbf, w2t + (size_t)l * HFF * D, ffn_b2 + l * D, val1,
        dst, val0bf, N, HFF, D);
    float* tmp = sin_; sin_ = sout_; sout_ = tmp;
  }
}